// Round 1
// baseline (48.120 us; speedup 1.0000x reference)
//
#include <hip/hip_runtime.h>

typedef __bf16 bf16x8 __attribute__((ext_vector_type(8)));
typedef float  f32x4  __attribute__((ext_vector_type(4)));

#define D100 100
#define NROWS (4096*64)          // 262144 rows of X
#define NTILES (NROWS/16)        // 16384 16-row tiles
#define NCT 7                    // col tiles: 7*16 = 112 >= 100
#define NKS 4                    // k steps:  4*32 = 128 >= 100
#define FRAG_ELEMS (NCT*NKS*64*8)  // 14336 bf16 fragment elements
#define NBLOCKS 1024
#define WAVES_TOTAL (NBLOCKS*4)

// ---------------------------------------------------------------------------
// Kernel 1: build M = W^T * S (in MFMA B-fragment order, bf16, zero-padded)
// and c = b * S (fp32). M[k][n] = sum_d W[d*100+k] * S[d*100+n].
// Fragment order: wsM[((ct*4+ks)*64 + lane)*8 + j] holds
//   M[ ks*32 + (lane>>4)*8 + j ][ ct*16 + (lane&15) ]
// ---------------------------------------------------------------------------
__global__ __launch_bounds__(256) void prep_kernel(
    const float* __restrict__ W, const float* __restrict__ bvec,
    const float* __restrict__ S, __bf16* __restrict__ wsM,
    float* __restrict__ wsc) {
  int tid = blockIdx.x * 256 + threadIdx.x;
  if (tid < FRAG_ELEMS) {
    int j    = tid & 7;
    int lane = (tid >> 3) & 63;
    int ks   = (tid >> 9) & 3;
    int ct   = tid >> 11;
    int k = ks * 32 + ((lane >> 4) * 8) + j;
    int n = ct * 16 + (lane & 15);
    float acc = 0.f;
    if (k < D100 && n < D100) {
      float a0 = 0.f, a1 = 0.f, a2 = 0.f, a3 = 0.f;
      for (int d = 0; d < D100; d += 4) {
        a0 += W[(d + 0) * D100 + k] * S[(d + 0) * D100 + n];
        a1 += W[(d + 1) * D100 + k] * S[(d + 1) * D100 + n];
        a2 += W[(d + 2) * D100 + k] * S[(d + 2) * D100 + n];
        a3 += W[(d + 3) * D100 + k] * S[(d + 3) * D100 + n];
      }
      acc = (a0 + a1) + (a2 + a3);
    }
    wsM[tid] = (__bf16)acc;
  } else if (tid < FRAG_ELEMS + 128) {
    int n = tid - FRAG_ELEMS;
    if (n < D100) {
      float a = 0.f;
      for (int d = 0; d < D100; ++d) a += bvec[d] * S[d * D100 + n];
      wsc[n] = a;
    }
  }
}

// ---------------------------------------------------------------------------
// Kernel 2: out[r][n] = sum_k x[r][k] * M[k][n] + c[n]
// One wave per 16-row tile, grid-stride. B fragments + bias in registers,
// A fragments loaded straight from global (fp32) and converted to bf16.
// ---------------------------------------------------------------------------
__global__ __launch_bounds__(256) void gemm_kernel(
    const float* __restrict__ x, const __bf16* __restrict__ wsM,
    const float* __restrict__ wsc, float* __restrict__ out) {
  const int lane = threadIdx.x & 63;
  const int l16  = lane & 15;
  const int lg   = lane >> 4;
  const int gwave = blockIdx.x * 4 + (threadIdx.x >> 6);

  // B fragments: constant across the whole kernel, keep in registers.
  bf16x8 bfrag[NCT][NKS];
  const bf16x8* wsMv = (const bf16x8*)wsM;
#pragma unroll
  for (int ct = 0; ct < NCT; ++ct)
#pragma unroll
    for (int ks = 0; ks < NKS; ++ks)
      bfrag[ct][ks] = wsMv[(ct * NKS + ks) * 64 + lane];

  float cval[NCT];
#pragma unroll
  for (int ct = 0; ct < NCT; ++ct) {
    int col = ct * 16 + l16;
    cval[ct] = (col < D100) ? wsc[col] : 0.f;
  }

  for (int tile = gwave; tile < NTILES; tile += WAVES_TOTAL) {
    const float* xr = x + (size_t)tile * (16 * D100) + l16 * D100;

    f32x4 acc[NCT];
#pragma unroll
    for (int ct = 0; ct < NCT; ++ct)
      acc[ct] = (f32x4){cval[ct], cval[ct], cval[ct], cval[ct]};

#pragma unroll
    for (int ks = 0; ks < NKS; ++ks) {
      bf16x8 af;
      const int k0 = ks * 32 + lg * 8;
      if (ks < 3) {
        f32x4 v0 = *(const f32x4*)(xr + k0);
        f32x4 v1 = *(const f32x4*)(xr + k0 + 4);
#pragma unroll
        for (int j = 0; j < 4; ++j) {
          af[j]     = (__bf16)v0[j];
          af[j + 4] = (__bf16)v1[j];
        }
      } else {
        // ks==3: k = 96 + lg*8 + j; only lg==0, j<4 (k=96..99) is valid.
        f32x4 v0 = {0.f, 0.f, 0.f, 0.f};
        if (lg == 0) v0 = *(const f32x4*)(xr + 96);
#pragma unroll
        for (int j = 0; j < 4; ++j) {
          af[j]     = (__bf16)v0[j];
          af[j + 4] = (__bf16)0.f;
        }
      }
#pragma unroll
      for (int ct = 0; ct < NCT; ++ct)
        acc[ct] = __builtin_amdgcn_mfma_f32_16x16x32_bf16(
            af, bfrag[ct][ks], acc[ct], 0, 0, 0);
    }

    // C layout: col = lane&15, row = (lane>>4)*4 + reg  (verified m89/m91)
    float* orow = out + (size_t)tile * 16 * D100 + (size_t)(lg * 4) * D100;
#pragma unroll
    for (int ct = 0; ct < NCT; ++ct) {
      int col = ct * 16 + l16;
      if (col < D100) {
#pragma unroll
        for (int r = 0; r < 4; ++r) orow[r * D100 + col] = acc[ct][r];
      }
    }
  }
}

extern "C" void kernel_launch(void* const* d_in, const int* in_sizes, int n_in,
                              void* d_out, int out_size, void* d_ws,
                              size_t ws_size, hipStream_t stream) {
  const float* x = (const float*)d_in[0];
  const float* W = (const float*)d_in[1];
  const float* b = (const float*)d_in[2];
  const float* S = (const float*)d_in[3];
  __bf16* wsM = (__bf16*)d_ws;
  float*  wsc = (float*)((char*)d_ws + (size_t)FRAG_ELEMS * 2);
  float*  out = (float*)d_out;

  hipLaunchKernelGGL(prep_kernel, dim3(57), dim3(256), 0, stream,
                     W, b, S, wsM, wsc);
  hipLaunchKernelGGL(gemm_kernel, dim3(NBLOCKS), dim3(256), 0, stream,
                     x, wsM, wsc, out);
}

// Round 2
// 45.888 us; speedup vs baseline: 1.0486x; 1.0486x over previous
//
#include <hip/hip_runtime.h>

typedef __bf16 bf16x8 __attribute__((ext_vector_type(8)));
typedef float  f32x4  __attribute__((ext_vector_type(4)));

#define D100 100
#define NROWS (4096*64)            // 262144 rows of X
#define NTILES (NROWS/16)          // 16384 16-row tiles
#define NCT 7                      // col tiles: 7*16 = 112 >= 100
#define NKS 4                      // k steps:  4*32 = 128 >= 100
#define FRAG_ELEMS (NCT*NKS*64*8)  // 14336 bf16 fragment elements (28672 B)
#define NBLK (NTILES/4)            // 4096 blocks, 4 waves each, 1 tile/wave

// ---------------------------------------------------------------------------
// Kernel 1: build M = W^T * S (in MFMA B-fragment order, bf16, zero-padded)
// and c = b * S (fp32). M[k][n] = sum_d W[d*100+k] * S[d*100+n].
// Fragment order: wsM[((ct*4+ks)*64 + lane)*8 + j] holds
//   M[ ks*32 + (lane>>4)*8 + j ][ ct*16 + (lane&15) ]
// ---------------------------------------------------------------------------
__global__ __launch_bounds__(256) void prep_kernel(
    const float* __restrict__ W, const float* __restrict__ bvec,
    const float* __restrict__ S, __bf16* __restrict__ wsM,
    float* __restrict__ wsc) {
  int tid = blockIdx.x * 256 + threadIdx.x;
  if (tid < FRAG_ELEMS) {
    int j    = tid & 7;
    int lane = (tid >> 3) & 63;
    int ks   = (tid >> 9) & 3;
    int ct   = tid >> 11;
    int k = ks * 32 + ((lane >> 4) * 8) + j;
    int n = ct * 16 + (lane & 15);
    float acc = 0.f;
    if (k < D100 && n < D100) {
      float a0 = 0.f, a1 = 0.f, a2 = 0.f, a3 = 0.f;
      for (int d = 0; d < D100; d += 4) {
        a0 += W[(d + 0) * D100 + k] * S[(d + 0) * D100 + n];
        a1 += W[(d + 1) * D100 + k] * S[(d + 1) * D100 + n];
        a2 += W[(d + 2) * D100 + k] * S[(d + 2) * D100 + n];
        a3 += W[(d + 3) * D100 + k] * S[(d + 3) * D100 + n];
      }
      acc = (a0 + a1) + (a2 + a3);
    }
    wsM[tid] = (__bf16)acc;
  } else if (tid < FRAG_ELEMS + 128) {
    int n = tid - FRAG_ELEMS;
    if (n < D100) {
      float a = 0.f;
      for (int d = 0; d < D100; ++d) a += bvec[d] * S[d * D100 + n];
      wsc[n] = a;
    }
  }
}

// ---------------------------------------------------------------------------
// Kernel 2: out[r][n] = sum_k x[r][k] * M[k][n] + c[n]
// 4 waves/block, ONE 16-row tile per wave (grid covers all tiles).
// B fragments staged in LDS (shared by all waves, lane-contiguous
// ds_read_b128 -> conflict-free). Output goes through a block-level LDS
// transpose buffer so global stores are aligned, coalesced f32x4.
// ---------------------------------------------------------------------------
__global__ __launch_bounds__(256) void gemm_kernel(
    const float* __restrict__ x, const __bf16* __restrict__ wsM,
    const float* __restrict__ wsc, float* __restrict__ out) {
  __shared__ __align__(16) __bf16 ldsB[FRAG_ELEMS];       // 28672 B
  __shared__ __align__(16) float  ldsOut[64 * D100];      // 25600 B

  const int t    = threadIdx.x;
  const int lane = t & 63;
  const int l16  = lane & 15;
  const int lg   = lane >> 4;
  const int w    = t >> 6;
  const int tile = blockIdx.x * 4 + w;

  // --- stage B fragments into LDS: 1792 x 16B chunks, 7 per thread ---
  {
    const f32x4* src = (const f32x4*)wsM;
    f32x4*       dst = (f32x4*)ldsB;
#pragma unroll
    for (int i = 0; i < 7; ++i) dst[i * 256 + t] = src[i * 256 + t];
  }

  // --- bias (L2-hot scalar loads) ---
  float cval[NCT];
#pragma unroll
  for (int ct = 0; ct < NCT; ++ct) {
    int col = ct * 16 + l16;
    cval[ct] = (col < D100) ? wsc[col] : 0.f;
  }

  // --- issue all A loads up front (7 x f32x4 per lane) ---
  const float* xr = x + (size_t)tile * (16 * D100) + l16 * D100;
  f32x4 xv[7];
#pragma unroll
  for (int ks = 0; ks < 3; ++ks) {
    xv[ks * 2]     = *(const f32x4*)(xr + ks * 32 + lg * 8);
    xv[ks * 2 + 1] = *(const f32x4*)(xr + ks * 32 + lg * 8 + 4);
  }
  xv[6] = (lg == 0) ? *(const f32x4*)(xr + 96) : (f32x4){0.f, 0.f, 0.f, 0.f};

  __syncthreads();  // ldsB ready

  f32x4 acc[NCT];
#pragma unroll
  for (int ct = 0; ct < NCT; ++ct)
    acc[ct] = (f32x4){cval[ct], cval[ct], cval[ct], cval[ct]};

  const bf16x8* Bv = (const bf16x8*)ldsB;
#pragma unroll
  for (int ks = 0; ks < NKS; ++ks) {
    bf16x8 af;
    if (ks < 3) {
      f32x4 v0 = xv[ks * 2], v1 = xv[ks * 2 + 1];
#pragma unroll
      for (int j = 0; j < 4; ++j) {
        af[j]     = (__bf16)v0[j];
        af[j + 4] = (__bf16)v1[j];
      }
    } else {
      f32x4 v0 = xv[6];  // zero for lg != 0
#pragma unroll
      for (int j = 0; j < 4; ++j) {
        af[j]     = (__bf16)v0[j];
        af[j + 4] = (__bf16)0.f;
      }
    }
#pragma unroll
    for (int ct = 0; ct < NCT; ++ct)
      acc[ct] = __builtin_amdgcn_mfma_f32_16x16x32_bf16(
          af, Bv[(ct * NKS + ks) * 64 + lane], acc[ct], 0, 0, 0);
  }

  // --- scatter accumulators into LDS transpose buffer ---
  // C layout: col = lane&15, row = (lane>>4)*4 + reg
#pragma unroll
  for (int ct = 0; ct < NCT; ++ct) {
    int col = ct * 16 + l16;
    if (col < D100) {
#pragma unroll
      for (int r = 0; r < 4; ++r)
        ldsOut[(w * 16 + lg * 4 + r) * D100 + col] = acc[ct][r];
    }
  }
  __syncthreads();  // ldsOut ready

  // --- fully coalesced, aligned f32x4 store of the 64x100 block tile ---
  f32x4*       ob = (f32x4*)(out + (size_t)blockIdx.x * (64 * D100));
  const f32x4* lo = (const f32x4*)ldsOut;
#pragma unroll
  for (int i = 0; i < 6; ++i) ob[i * 256 + t] = lo[i * 256 + t];
  if (t < 64) ob[1536 + t] = lo[1536 + t];
}

extern "C" void kernel_launch(void* const* d_in, const int* in_sizes, int n_in,
                              void* d_out, int out_size, void* d_ws,
                              size_t ws_size, hipStream_t stream) {
  const float* x = (const float*)d_in[0];
  const float* W = (const float*)d_in[1];
  const float* b = (const float*)d_in[2];
  const float* S = (const float*)d_in[3];
  __bf16* wsM = (__bf16*)d_ws;
  float*  wsc = (float*)((char*)d_ws + (size_t)FRAG_ELEMS * 2);
  float*  out = (float*)d_out;

  hipLaunchKernelGGL(prep_kernel, dim3(57), dim3(256), 0, stream,
                     W, b, S, wsM, wsc);
  hipLaunchKernelGGL(gemm_kernel, dim3(NBLK), dim3(256), 0, stream,
                     x, wsM, wsc, out);
}